// Round 14
// baseline (482.425 us; speedup 1.0000x reference)
//
#include <hip/hip_runtime.h>
#include <hip/hip_bf16.h>
#include <math.h>

#define T_LEN 2048
#define RC 256
#define DIM 1024
#define VOCAB 50257
#define NT2 16              // K tiles: 1024 / 64
#define SLOTW 16384         // ushorts per operand slot: 256 rows x 64 cols
#define HALFW 8192          // ushorts per half-tile: 128 rows x 64 cols

using short8  = __attribute__((ext_vector_type(8))) short;
using f32x4   = __attribute__((ext_vector_type(4))) float;

#define VMCNT(n) asm volatile("s_waitcnt vmcnt(" #n ")" ::: "memory")
#define LGKM0()  asm volatile("s_waitcnt lgkmcnt(0)" ::: "memory")
#define SCHED_FENCE() __builtin_amdgcn_sched_barrier(0)

__device__ __forceinline__ unsigned short f2bf(float f) {
    unsigned int u = __float_as_uint(f);
    u += 0x7fffu + ((u >> 16) & 1u);          // round-to-nearest-even
    return (unsigned short)(u >> 16);
}

// HW packed cvt: dst = {lo16=bf16(a), hi16=bf16(b)}, RNE
__device__ __forceinline__ unsigned int cvt_pk_bf16(float a, float b) {
    unsigned int r;
    asm volatile("v_cvt_pk_bf16_f32 %0, %1, %2" : "=v"(r) : "v"(a), "v"(b));
    return r;
}

__device__ __forceinline__ void async_load16(void* lds, const void* g) {
    __builtin_amdgcn_global_load_lds(
        (const __attribute__((address_space(1))) void*)g,
        (__attribute__((address_space(3))) void*)lds,
        16, 0, 0);
}

// ---------------- K1: MU = gather(token_to_mu_w^T, ids) + pos ----------------
__global__ __launch_bounds__(256) void mu_kernel(
    const int* __restrict__ ids, const float* __restrict__ tokw,
    const float* __restrict__ pos, float* __restrict__ mu) {
    int t = blockIdx.x, k = threadIdx.x;
    int id = ids[t];
    float v = tokw[(size_t)k * VOCAB + id] + pos[t * RC + k];
    mu[t * RC + k] = v;
}

// ---------------- K2: h_pre = gelu(MU @ w1^T + b1) ----------------
__global__ __launch_bounds__(256) void gemm1_gelu_kernel(
    const float* __restrict__ mu, const float* __restrict__ w1,
    const float* __restrict__ b1, float* __restrict__ hpre) {
    __shared__ float xs[16][RC];
    const int tg = blockIdx.x, ng = blockIdx.y, tid = threadIdx.x;
    const int t0 = tg * 16;
    {
        const float4* src = (const float4*)(mu + (size_t)t0 * RC);
        float4* dst = (float4*)&xs[0][0];
        #pragma unroll
        for (int i = 0; i < 4; ++i) dst[tid + 256 * i] = src[tid + 256 * i];
    }
    __syncthreads();
    const int d = ng * 256 + tid;
    float acc[16];
    const float bias = b1[d];
    #pragma unroll
    for (int t = 0; t < 16; ++t) acc[t] = bias;
    const float4* w1r = (const float4*)(w1 + (size_t)d * RC);
    for (int k4 = 0; k4 < RC / 4; ++k4) {
        const float4 w = w1r[k4];
        #pragma unroll
        for (int t = 0; t < 16; ++t) {
            const float4 xv = *(const float4*)&xs[t][k4 * 4];
            acc[t] += w.x * xv.x + w.y * xv.y + w.z * xv.z + w.w * xv.w;
        }
    }
    #pragma unroll
    for (int t = 0; t < 16; ++t) {
        float x = acc[t];
        float g = 0.5f * x * (1.0f + erff(x * 0.70710678118654752f));
        hpre[(size_t)(t0 + t) * DIM + d] = g;
    }
}

// ---------------- K3: LayerNorm -> bf16 h ----------------
__global__ __launch_bounds__(256) void ln_kernel(
    const float* __restrict__ hpre, const float* __restrict__ lnw,
    const float* __restrict__ lnb, unsigned short* __restrict__ h) {
    const int t = blockIdx.x, tid = threadIdx.x;
    const float4 v = ((const float4*)(hpre + (size_t)t * DIM))[tid];
    float s  = v.x + v.y + v.z + v.w;
    float ss = v.x * v.x + v.y * v.y + v.z * v.z + v.w * v.w;
    #pragma unroll
    for (int off = 32; off > 0; off >>= 1) {
        s  += __shfl_down(s, off, 64);
        ss += __shfl_down(ss, off, 64);
    }
    __shared__ float red[8];
    const int wid = tid >> 6, lane = tid & 63;
    if (lane == 0) { red[wid] = s; red[4 + wid] = ss; }
    __syncthreads();
    const float S  = red[0] + red[1] + red[2] + red[3];
    const float SS = red[4] + red[5] + red[6] + red[7];
    const float mean = S * (1.0f / DIM);
    const float var  = SS * (1.0f / DIM) - mean * mean;
    const float inv  = 1.0f / sqrtf(var + 1e-6f);
    const float4 wv = ((const float4*)lnw)[tid];
    const float4 bv = ((const float4*)lnb)[tid];
    ushort4 o;
    o.x = f2bf((v.x - mean) * inv * wv.x + bv.x);
    o.y = f2bf((v.y - mean) * inv * wv.y + bv.y);
    o.z = f2bf((v.z - mean) * inv * wv.z + bv.z);
    o.w = f2bf((v.w - mean) * inv * wv.w + bv.w);
    ((ushort4*)h)[(size_t)t * (DIM / 4) + tid] = o;
}

// ---------------- K4: w2 f32 -> bf16 (HW packed cvt) ----------------
__global__ __launch_bounds__(256) void cvt_kernel(
    const float* __restrict__ src, unsigned int* __restrict__ dst, int n8) {
    int i = blockIdx.x * 256 + threadIdx.x;
    const int stride = gridDim.x * 256;
    for (; i < n8; i += stride) {
        const float4 a = ((const float4*)src)[2 * i];
        const float4 b = ((const float4*)src)[2 * i + 1];
        uint4 o;
        o.x = cvt_pk_bf16(a.x, a.y);
        o.y = cvt_pk_bf16(a.z, a.w);
        o.z = cvt_pk_bf16(b.x, b.y);
        o.w = cvt_pk_bf16(b.z, b.w);
        ((uint4*)dst)[i] = o;
    }
}

// ---------------- K5: logits = h @ w2^T + b2 (m201 8-phase port) ----------
// 256x256 tile, BK=64, 512 threads = 8 waves (2M x 4N), wave tile 128x64.
// dbuf-2 LDS at HALF-TILE granularity (128 KiB).  Per K-tile: 4 phases =
// 4 C-quadrants x 16 MFMA.  Staging: (k+1).Ah1@p0, (k+2).Bh0@p1,
// (k+2).Bh1@p2, (k+2).Ah0@p3; single counted vmcnt(6) per K-tile at p3
// (retires exactly through (k+1).Ah1 -- 3 half-tiles in flight).
// Swizzle: granule g -> g ^ (row&7) (2-way max, free); source preswizzled.
__device__ __forceinline__ void stage_halfA(
    const unsigned short* __restrict__ A, unsigned short* dst,
    int m0, int half, int kt, int tid) {
    #pragma unroll
    for (int p = 0; p < 2; ++p) {
        const int idx = p * 512 + tid;          // granule 0..1023
        const int r   = idx >> 3;               // row within half
        const int gl  = (idx & 7) ^ (r & 7);    // logical (source) granule
        async_load16(dst + (size_t)idx * 8,
                     A + (size_t)(m0 + half * 128 + r) * DIM + kt * 64 + gl * 8);
    }
}
__device__ __forceinline__ void stage_halfB(
    const unsigned short* __restrict__ B, unsigned short* dst,
    int n0, int half, int kt, int tid) {
    #pragma unroll
    for (int p = 0; p < 2; ++p) {
        const int idx = p * 512 + tid;
        const int r   = idx >> 3;
        const int gl  = (idx & 7) ^ (r & 7);
        int row = n0 + half * 128 + r; if (row > VOCAB - 1) row = VOCAB - 1;
        async_load16(dst + (size_t)idx * 8,
                     B + (size_t)row * DIM + kt * 64 + gl * 8);
    }
}

__global__ __launch_bounds__(512, 1) void gemm2_kernel(
    const unsigned short* __restrict__ A, const unsigned short* __restrict__ B,
    const float* __restrict__ b2, float* __restrict__ out) {
    __shared__ unsigned short As[2 * SLOTW];   // 64 KiB
    __shared__ unsigned short Bs[2 * SLOTW];   // 64 KiB

    const int tid  = threadIdx.x;
    // T1: bijective XCD swizzle (gridDim.x = 1576 = 8*197), M-fastest
    const int cpx  = gridDim.x >> 3;   // 197
    const int wgid = (blockIdx.x & 7) * cpx + (blockIdx.x >> 3);
    const int m0   = (wgid & 7) << 8;
    const int n0   = (wgid >> 3) << 8;

    const int lane = tid & 63;
    const int lr   = lane & 15;
    const int lk   = lane >> 4;
    const int wid  = tid >> 6;
    const int wr   = wid >> 2;          // 0..1  (M)
    const int wc   = wid & 3;           // 0..3  (N)
    const int sx   = lr & 7;            // row&7 term, constant per lane

    f32x4 acc[8][4];
    #pragma unroll
    for (int m = 0; m < 8; ++m)
        #pragma unroll
        for (int n = 0; n < 4; ++n) acc[m][n] = {0.f, 0.f, 0.f, 0.f};

    // prologue: tile0 all 4 halves + tile1 {Bh0,Bh1,Ah0}  (14 loads)
    stage_halfB(B, Bs,                 n0, 0, 0, tid);
    stage_halfB(B, Bs + HALFW,         n0, 1, 0, tid);
    stage_halfA(A, As,                 m0, 0, 0, tid);
    stage_halfA(A, As + HALFW,         m0, 1, 0, tid);
    stage_halfB(B, Bs + SLOTW,         n0, 0, 1, tid);
    stage_halfB(B, Bs + SLOTW + HALFW, n0, 1, 1, tid);
    stage_halfA(A, As + SLOTW,         m0, 0, 1, tid);
    VMCNT(6);                          // tile 0's 8 loads retired
    __builtin_amdgcn_s_barrier();

    short8 af[8], bfr[8];              // af: 4 m-frags x 2 kk; bfr: 4 n x 2 kk

    #pragma unroll 1
    for (int k = 0; k < NT2; ++k) {
        const unsigned short* As_t = As + (k & 1) * SLOTW;
        const unsigned short* Bs_t = Bs + (k & 1) * SLOTW;
        unsigned short* As_n  = As + ((k + 1) & 1) * SLOTW;  // (k+1) slot
        unsigned short* As_n2 = As + (k & 1) * SLOTW;        // (k+2) slot
        unsigned short* Bs_n2 = Bs + (k & 1) * SLOTW;

        // ---- p0: read A(mh0) + B(all); stage (k+1).Ah1; Q(0,0) ----
        #pragma unroll
        for (int mi = 0; mi < 4; ++mi) {
            const int R = wr * 128 + mi * 16 + lr;
            #pragma unroll
            for (int kk = 0; kk < 2; ++kk)
                af[mi * 2 + kk] =
                    *(const short8*)(As_t + R * 64 + (((kk * 4 + lk) ^ sx) << 3));
        }
        #pragma unroll
        for (int ni = 0; ni < 4; ++ni) {
            const int R = wc * 64 + ni * 16 + lr;
            #pragma unroll
            for (int kk = 0; kk < 2; ++kk)
                bfr[ni * 2 + kk] =
                    *(const short8*)(Bs_t + R * 64 + (((kk * 4 + lk) ^ sx) << 3));
        }
        if (k + 1 < NT2) stage_halfA(A, As_n + HALFW, m0, 1, k + 1, tid);
        __builtin_amdgcn_s_barrier();
        LGKM0();
        SCHED_FENCE();                 // rule 18
        __builtin_amdgcn_s_setprio(1);
        #pragma unroll
        for (int mi = 0; mi < 4; ++mi)
            #pragma unroll
            for (int ni = 0; ni < 2; ++ni)
                #pragma unroll
                for (int kk = 0; kk < 2; ++kk)
                    acc[mi][ni] = __builtin_amdgcn_mfma_f32_16x16x32_bf16(
                        af[mi * 2 + kk], bfr[ni * 2 + kk], acc[mi][ni], 0, 0, 0);
        __builtin_amdgcn_s_setprio(0);
        __builtin_amdgcn_s_barrier();

        // ---- p1: stage (k+2).Bh0; Q(0,1) ----
        if (k + 2 < NT2) stage_halfB(B, Bs_n2, n0, 0, k + 2, tid);
        __builtin_amdgcn_s_setprio(1);
        #pragma unroll
        for (int mi = 0; mi < 4; ++mi)
            #pragma unroll
            for (int ni = 2; ni < 4; ++ni)
                #pragma unroll
                for (int kk = 0; kk < 2; ++kk)
                    acc[mi][ni] = __builtin_amdgcn_mfma_f32_16x16x32_bf16(
                        af[mi * 2 + kk], bfr[ni * 2 + kk], acc[mi][ni], 0, 0, 0);
        __builtin_amdgcn_s_setprio(0);
        __builtin_amdgcn_s_barrier();

        // ---- p2: read A(mh1); stage (k+2).Bh1; Q(1,0) ----
        #pragma unroll
        for (int mi = 0; mi < 4; ++mi) {
            const int R = wr * 128 + (mi + 4) * 16 + lr;
            #pragma unroll
            for (int kk = 0; kk < 2; ++kk)
                af[mi * 2 + kk] =
                    *(const short8*)(As_t + R * 64 + (((kk * 4 + lk) ^ sx) << 3));
        }
        if (k + 2 < NT2) stage_halfB(B, Bs_n2 + HALFW, n0, 1, k + 2, tid);
        __builtin_amdgcn_s_barrier();
        LGKM0();
        SCHED_FENCE();                 // rule 18
        __builtin_amdgcn_s_setprio(1);
        #pragma unroll
        for (int mi = 0; mi < 4; ++mi)
            #pragma unroll
            for (int ni = 0; ni < 2; ++ni)
                #pragma unroll
                for (int kk = 0; kk < 2; ++kk)
                    acc[mi + 4][ni] = __builtin_amdgcn_mfma_f32_16x16x32_bf16(
                        af[mi * 2 + kk], bfr[ni * 2 + kk], acc[mi + 4][ni], 0, 0, 0);
        __builtin_amdgcn_s_setprio(0);
        __builtin_amdgcn_s_barrier();

        // ---- p3: stage (k+2).Ah0; Q(1,1); vmcnt ----
        if (k + 2 < NT2) stage_halfA(A, As_n2, m0, 0, k + 2, tid);
        __builtin_amdgcn_s_setprio(1);
        #pragma unroll
        for (int mi = 0; mi < 4; ++mi)
            #pragma unroll
            for (int ni = 2; ni < 4; ++ni)
                #pragma unroll
                for (int kk = 0; kk < 2; ++kk)
                    acc[mi + 4][ni] = __builtin_amdgcn_mfma_f32_16x16x32_bf16(
                        af[mi * 2 + kk], bfr[ni * 2 + kk], acc[mi + 4][ni], 0, 0, 0);
        __builtin_amdgcn_s_setprio(0);
        if (k < NT2 - 2)       { VMCNT(6); }   // 3 half-tiles stay in flight
        else if (k == NT2 - 2) { VMCNT(0); }   // drain before last tile
        __builtin_amdgcn_s_barrier();
    }

    // epilogue: C row = frag_row + (lane>>4)*4 + j, col = lane&15
    float bias[4]; int col[4]; bool ok[4];
    #pragma unroll
    for (int n = 0; n < 4; ++n) {
        col[n] = n0 + wc * 64 + n * 16 + lr;
        ok[n]  = col[n] < VOCAB;
        bias[n] = ok[n] ? b2[col[n]] : 0.f;
    }
    #pragma unroll
    for (int m = 0; m < 8; ++m) {
        const int row = m0 + wr * 128 + m * 16 + lk * 4;
        #pragma unroll
        for (int n = 0; n < 4; ++n) {
            if (ok[n]) {
                #pragma unroll
                for (int j = 0; j < 4; ++j)
                    out[(size_t)(row + j) * VOCAB + col[n]] = acc[m][n][j] + bias[n];
            }
        }
    }
}

extern "C" void kernel_launch(void* const* d_in, const int* in_sizes, int n_in,
                              void* d_out, int out_size, void* d_ws, size_t ws_size,
                              hipStream_t stream) {
    (void)in_sizes; (void)n_in; (void)out_size; (void)ws_size;
    const int*   ids  = (const int*)d_in[0];
    const float* tokw = (const float*)d_in[1];
    const float* pos  = (const float*)d_in[2];
    const float* w1   = (const float*)d_in[3];
    const float* b1   = (const float*)d_in[4];
    const float* lnw  = (const float*)d_in[5];
    const float* lnb  = (const float*)d_in[6];
    const float* w2   = (const float*)d_in[7];
    const float* b2   = (const float*)d_in[8];

    float* logits = (float*)d_out;
    float* mu_out = logits + (size_t)T_LEN * VOCAB;            // MU output region

    unsigned short* w2b = (unsigned short*)d_ws;               // w2 bf16 (103 MB)
    unsigned short* hb  = (unsigned short*)((char*)d_ws + (size_t)VOCAB * DIM * 2);
    float* hpre = logits;   // scratch in logits region; fully overwritten by K5

    mu_kernel<<<dim3(T_LEN), dim3(256), 0, stream>>>(ids, tokw, pos, mu_out);
    gemm1_gelu_kernel<<<dim3(T_LEN / 16, DIM / 256), dim3(256), 0, stream>>>(
        mu_out, w1, b1, hpre);
    ln_kernel<<<dim3(T_LEN), dim3(256), 0, stream>>>(hpre, lnw, lnb, hb);
    cvt_kernel<<<dim3(2048), dim3(256), 0, stream>>>(
        w2, (unsigned int*)w2b, (int)((size_t)VOCAB * DIM / 8));
    const int ntiles_n = (VOCAB + 255) / 256;   // 197
    gemm2_kernel<<<dim3(8 * ntiles_n), dim3(512), 0, stream>>>(hb, w2b, b2, logits);
}